// Round 1
// baseline (497.562 us; speedup 1.0000x reference)
//
#include <hip/hip_runtime.h>
#include <math.h>

#define TT 2048
#define HH 2048
#define NSTEP 16
#define EPSF 1e-8f
#define BETA 0.1f

// ---------------- Kernel 1: segment-sum of hidden_state over T ----------------
// grid: (HH/256, 64) ; block 256. Each thread owns one h column of one (b,n),
// 16 register accumulators, scalar-uniform switch on step bucket.
__global__ __launch_bounds__(256) void k_segsum(const float* __restrict__ hidden,
                                                const int* __restrict__ step,
                                                float* __restrict__ ssum) {
  const int bn  = blockIdx.y;
  const int col = blockIdx.x * 256 + threadIdx.x;

  __shared__ int s_step[TT];
  for (int t = threadIdx.x; t < TT; t += 256) s_step[t] = step[bn * TT + t];
  __syncthreads();

  const float* hp = hidden + (size_t)bn * TT * HH + col;

  float acc[NSTEP];
#pragma unroll
  for (int k = 0; k < NSTEP; ++k) acc[k] = 0.f;

  for (int t = 0; t < TT; t += 8) {
    float v[8];
#pragma unroll
    for (int u = 0; u < 8; ++u) v[u] = hp[(size_t)(t + u) * HH];
#pragma unroll
    for (int u = 0; u < 8; ++u) {
      const int s = __builtin_amdgcn_readfirstlane(s_step[t + u]);
      switch (s) {
#define SEG_CASE(K) case K: acc[K] += v[u]; break;
        SEG_CASE(0)  SEG_CASE(1)  SEG_CASE(2)  SEG_CASE(3)
        SEG_CASE(4)  SEG_CASE(5)  SEG_CASE(6)  SEG_CASE(7)
        SEG_CASE(8)  SEG_CASE(9)  SEG_CASE(10) SEG_CASE(11)
        SEG_CASE(12) SEG_CASE(13) SEG_CASE(14) SEG_CASE(15)
#undef SEG_CASE
      }
    }
  }

  float* op = ssum + (size_t)bn * NSTEP * HH + col;
#pragma unroll
  for (int k = 0; k < NSTEP; ++k) op[(size_t)k * HH] = acc[k];
}

// ---------------- Kernel 2: per-(b,n) cosine weights -> text_logits ----------------
__global__ __launch_bounds__(256) void k_bn(const float* __restrict__ pol,
                                            const float* __restrict__ refp,
                                            const int* __restrict__ step,
                                            const float* __restrict__ ssum,
                                            float* __restrict__ text_logits) {
  const int bn  = blockIdx.x;
  const int b   = bn >> 3;
  const int bn0 = b << 3;

  __shared__ float cnt[NSTEP], cnt0[NSTEP], lsum[NSTEP], wgt[NSTEP];
  if (threadIdx.x < NSTEP) {
    cnt[threadIdx.x] = 0.f; cnt0[threadIdx.x] = 0.f; lsum[threadIdx.x] = 0.f;
  }
  __syncthreads();

  for (int t = threadIdx.x; t < TT; t += 256) {
    const int s = step[bn * TT + t];
    atomicAdd(&cnt[s], 1.f);
    atomicAdd(&lsum[s], pol[bn * TT + t] - refp[bn * TT + t]);
    const int s0 = step[bn0 * TT + t];
    atomicAdd(&cnt0[s0], 1.f);
  }
  __syncthreads();

  const int wave = threadIdx.x >> 6;
  const int lane = threadIdx.x & 63;

  for (int si = 0; si < 4; ++si) {
    const int s = wave * 4 + si;
    const float c  = fmaxf(cnt[s],  1.f);
    const float c0 = fmaxf(cnt0[s], 1.f);
    const float ic  = 1.f / c;
    const float ic0 = 1.f / c0;
    const float* p  = ssum + ((size_t)bn  * NSTEP + s) * HH;
    const float* p0 = ssum + ((size_t)bn0 * NSTEP + s) * HH;
    float dot = 0.f, nn = 0.f, rr = 0.f;
    for (int h = lane; h < HH; h += 64) {
      const float a  = p[h]  * ic;
      const float r0 = p0[h] * ic0;
      dot += a * r0; nn += a * a; rr += r0 * r0;
    }
#pragma unroll
    for (int off = 32; off > 0; off >>= 1) {
      dot += __shfl_down(dot, off);
      nn  += __shfl_down(nn,  off);
      rr  += __shfl_down(rr,  off);
    }
    if (lane == 0) {
      const float nrm = fmaxf(sqrtf(nn), EPSF);
      const float rn  = fmaxf(sqrtf(rr), EPSF);
      const float cosv = dot / (nrm * rn);
      const bool valid = (cnt[s] > 0.f) && (cnt0[s] > 0.f) && (s >= 1);
      wgt[s] = valid ? (cosv + 1.f) : 0.f;
    }
  }
  __syncthreads();

  if (threadIdx.x == 0) {
    float wsum = 0.f, tw = 0.f;
#pragma unroll
    for (int s = 0; s < NSTEP; ++s) {
      const float w = wgt[s];
      wsum += w * (lsum[s] / fmaxf(cnt[s], 1.f));
      tw   += w;
    }
    text_logits[bn] = (tw > 0.f) ? (wsum / fmaxf(tw, EPSF)) : 0.f;
  }
}

// ---------------- Kernel 3: LambdaRank loss + reward means ----------------
__device__ inline float softplus_f(float x) {
  return fmaxf(x, 0.f) + log1pf(expf(-fabsf(x)));
}

__global__ __launch_bounds__(256) void k_final(const float* __restrict__ pol,
                                               const float* __restrict__ refp,
                                               const float* __restrict__ labels,
                                               const float* __restrict__ text_logits,
                                               float* __restrict__ out) {
  const int which = blockIdx.x;
  const int wave = threadIdx.x >> 6;
  const int lane = threadIdx.x & 63;
  __shared__ float red[4];

  if (which == 0) {
    // LambdaRank over (B=8, N=8): 64 lanes, one (b,i) each.
    float part = 0.f;
    if (threadIdx.x < 64) {
      const int b = threadIdx.x >> 3, i = threadIdx.x & 7;
      const float pi = text_logits[b * 8 + i];
      const float li = labels[b * 8 + i];
#pragma unroll
      for (int j = 0; j < 8; ++j) {
        const float ld = li - labels[b * 8 + j];
        const float sg = (ld > 0.f) ? 1.f : ((ld < 0.f) ? -1.f : 0.f);
        const float z  = (pi - text_logits[b * 8 + j]) * sg;
        part += softplus_f(-z);  // -log_sigmoid(z)
      }
    }
    if (wave == 0) {
#pragma unroll
      for (int off = 32; off > 0; off >>= 1) part += __shfl_down(part, off);
      if (lane == 0) {
        const float lr = part / (56.f * 8.f);   // /(N*(N-1)) then mean over b
        out[0] = softplus_f(-BETA * lr);        // -log_sigmoid(beta*lr)
      }
    }
  } else {
    const int n = (which == 1) ? 0 : 7;
    float s = 0.f;
    for (int i = threadIdx.x; i < 8 * TT; i += 256) {
      const int b = i >> 11, t = i & (TT - 1);
      const size_t idx = ((size_t)(b * 8 + n)) * TT + t;
      s += pol[idx] - refp[idx];
    }
#pragma unroll
    for (int off = 32; off > 0; off >>= 1) s += __shfl_down(s, off);
    if (lane == 0) red[wave] = s;
    __syncthreads();
    if (threadIdx.x == 0)
      out[which] = (red[0] + red[1] + red[2] + red[3]) / (8.f * TT);
  }
}

extern "C" void kernel_launch(void* const* d_in, const int* in_sizes, int n_in,
                              void* d_out, int out_size, void* d_ws, size_t ws_size,
                              hipStream_t stream) {
  const float* pol    = (const float*)d_in[0];
  const float* refp   = (const float*)d_in[1];
  const float* hidden = (const float*)d_in[2];
  const int*   step   = (const int*)d_in[3];
  const float* labels = (const float*)d_in[4];
  float* out = (float*)d_out;

  float* ssum        = (float*)d_ws;                       // 64*16*2048 floats = 8 MB
  float* text_logits = ssum + (size_t)64 * NSTEP * HH;     // 64 floats

  dim3 g1(HH / 256, 64);
  k_segsum<<<g1, 256, 0, stream>>>(hidden, step, ssum);
  k_bn<<<64, 256, 0, stream>>>(pol, refp, step, ssum, text_logits);
  k_final<<<3, 256, 0, stream>>>(pol, refp, labels, text_logits, out);
}